// Round 1
// baseline (215.557 us; speedup 1.0000x reference)
//
#include <hip/hip_runtime.h>
#include <math.h>

// e0 = 4*((1/3)^12 - (1/3)^6); 0.5*pe = 2*(c12 - c6) - 0.5*e0
static constexpr float HALF_NEG_E0 = 2.739720872e-3f; // -0.5*e0

#define T 256           // threads per block
#define SHIFT 10
#define BK 1024         // nodes per bucket (lid fits in 10 bits)
#define S2 16           // sub-blocks per bucket in p4a
#define FPSCALE 512.0f  // |f| <= 59.5 -> |int| <= 30450 < 32767
#define INV_FPSCALE (1.0f / 512.0f)

// ---- Phase 3 (fused): count -> reserve (global atomic per bucket) ->
//      compute -> LDS bucket-grouped staging -> coalesced flush --------------
// Requires NB <= 128, GPB*4 >= 128, GPB <= 2*T (launcher guards).
// Exactly <=2 int4-groups per thread: dst cached in registers across passes,
// all bv loads issued straight-line for latency overlap.
__global__ __launch_bounds__(T)
void p3_fused(const float* __restrict__ bv, const int* __restrict__ dst,
              unsigned* __restrict__ gcur, int2* __restrict__ sorted,
              float* __restrict__ energy, int E, int NB, int GPB, int cap)
{
    extern __shared__ int smem[];
    const int capb = GPB << 2;                    // max entries per block
    int2*          s_ent = (int2*)smem;           // [capb] packed (lo,hi)
    unsigned char* s_bkt = (unsigned char*)(smem + 2 * capb); // [capb]
    int* lcur = smem + 2 * capb + (capb + 3) / 4; // [NB] counts -> cursors
    int* gml  = lcur + NB;                        // [NB]

    const int r = blockIdx.x;
    const int t = threadIdx.x;

    const int G  = (E + 3) >> 2;
    const int gs = r * GPB;
    const int ge = min(G, gs + GPB);
    const int4*   __restrict__ d4  = (const int4*)dst;
    const float4* __restrict__ bv4 = (const float4*)bv;

    const int g0 = gs + t;
    const int g1 = gs + t + T;
    const bool v0 = g0 < ge;
    const bool v1 = g1 < ge;
    const bool f0 = v0 && ((g0 << 2) + 3 < E);    // full group of 4
    const bool f1 = v1 && ((g1 << 2) + 3 < E);

    // ---- issue dst loads once, keep in registers for both passes ----------
    int4 dA, dB;
    if (f0) dA = d4[g0];
    if (f1) dB = d4[g1];

    for (int b = t; b < NB; b += T) lcur[b] = 0;
    __syncthreads();

    // ---- pass A: local bucket histogram (native LDS int atomics) -----------
    if (f0) {
        atomicAdd(&lcur[((unsigned)dA.x) >> SHIFT], 1);
        atomicAdd(&lcur[((unsigned)dA.y) >> SHIFT], 1);
        atomicAdd(&lcur[((unsigned)dA.z) >> SHIFT], 1);
        atomicAdd(&lcur[((unsigned)dA.w) >> SHIFT], 1);
    } else if (v0) {
        for (int e = g0 << 2; e < E; ++e)
            atomicAdd(&lcur[((unsigned)dst[e]) >> SHIFT], 1);
    }
    if (f1) {
        atomicAdd(&lcur[((unsigned)dB.x) >> SHIFT], 1);
        atomicAdd(&lcur[((unsigned)dB.y) >> SHIFT], 1);
        atomicAdd(&lcur[((unsigned)dB.z) >> SHIFT], 1);
        atomicAdd(&lcur[((unsigned)dB.w) >> SHIFT], 1);
    } else if (v1) {
        for (int e = g1 << 2; e < E; ++e)
            atomicAdd(&lcur[((unsigned)dst[e]) >> SHIFT], 1);
    }
    __syncthreads();

    // ---- 128-wide exclusive scan of local counts (NB <= 128) ---------------
    int* sc = (int*)s_ent;                        // reuse staging
    if (t < 128) sc[t] = (t < NB) ? lcur[t] : 0;
    __syncthreads();
#pragma unroll
    for (int off = 1; off < 128; off <<= 1) {
        int a0 = (t < 128 && t >= off) ? sc[t - off] : 0;
        __syncthreads();
        if (t < 128) sc[t] += a0;
        __syncthreads();
    }
    // ---- reserve space in each bucket's region (one global atomic each) ----
    // gml only consumed at flush -> atomic return latency hides under pass B
    if (t < NB) {
        int cnt = lcur[t];
        int ex  = sc[t] - cnt;                    // exclusive prefix
        unsigned ret = atomicAdd(&gcur[t], (unsigned)cnt);
        gml[t]  = t * cap + (int)ret - ex;
        lcur[t] = ex;                             // becomes slot cursor
    }
    __syncthreads();

    // ---- pass B: compute forces + energy, stage bucket-grouped -------------
    float esum = 0.0f;

    auto edge1 = [&](float x, float y, float z, int node) {
        float r2  = x * x + y * y + z * z;
        float inv = 1.0f / r2;
        float c6  = inv * inv * inv;
        float c12 = c6 * c6;
        esum += 2.0f * (c12 - c6) + HALF_NEG_E0;
        float fs = -24.0f * (2.0f * c12 - c6) * inv * FPSCALE;
        int ix = __float2int_rn(fs * x);
        int iy = __float2int_rn(fs * y);
        int iz = __float2int_rn(fs * z);
        int b  = ((unsigned)node) >> SHIFT;
        int slot = atomicAdd(&lcur[b], 1);        // native LDS int atomic
        s_ent[slot] = make_int2((ix & 0xffff) | (iy << 16),
                                (iz & 0xffff) | ((node & (BK - 1)) << 16));
        s_bkt[slot] = (unsigned char)b;
    };

    // issue all bv loads up front (both groups) for max latency overlap
    float4 aA, bA, cA, aB, bB, cB;
    if (f0) { aA = bv4[3 * g0 + 0]; bA = bv4[3 * g0 + 1]; cA = bv4[3 * g0 + 2]; }
    if (f1) { aB = bv4[3 * g1 + 0]; bB = bv4[3 * g1 + 1]; cB = bv4[3 * g1 + 2]; }

    if (f0) {
        edge1(aA.x, aA.y, aA.z, dA.x);
        edge1(aA.w, bA.x, bA.y, dA.y);
        edge1(bA.z, bA.w, cA.x, dA.z);
        edge1(cA.y, cA.z, cA.w, dA.w);
    } else if (v0) {
        for (int e = g0 << 2; e < E; ++e)
            edge1(bv[3 * e], bv[3 * e + 1], bv[3 * e + 2], dst[e]);
    }
    if (f1) {
        edge1(aB.x, aB.y, aB.z, dB.x);
        edge1(aB.w, bB.x, bB.y, dB.y);
        edge1(bB.z, bB.w, cB.x, dB.z);
        edge1(cB.y, cB.z, cB.w, dB.w);
    } else if (v1) {
        for (int e = g1 << 2; e < E; ++e)
            edge1(bv[3 * e], bv[3 * e + 1], bv[3 * e + 2], dst[e]);
    }
    __syncthreads();

    // ---- flush: bucket order -> contiguous runs ----------------------------
    const int nloc = max(0, min(E, ge << 2) - (gs << 2));
    for (int i = t; i < nloc; i += T) {
        int2 e = s_ent[i];
        sorted[gml[(int)s_bkt[i]] + i] = e;
    }

    // ---- energy: wave shuffle -> LDS -> one global atomic per block --------
#pragma unroll
    for (int off = 32; off > 0; off >>= 1)
        esum += __shfl_down(esum, off, 64);
    __shared__ float wsum[T / 64];
    const int wid = t >> 6, lid = t & 63;
    if (lid == 0) wsum[wid] = esum;
    __syncthreads();
    if (t == 0) {
        float s = 0.0f;
        for (int w = 0; w < T / 64; ++w) s += wsum[w];
        unsafeAtomicAdd(energy, s);
    }
}

// ------- Phase 4a: per-(bucket, sub-chunk) LDS reduce -> global int atomics -
// partial buffer eliminated: each block atomically merges its LDS accumulator
// into accum[node*3+c] (int adds = order-independent, bit-deterministic).
__global__ __launch_bounds__(T)
void p4a_reduce(const int2* __restrict__ sorted, const unsigned* __restrict__ gcur,
                int* __restrict__ accum, int cap)
{
    __shared__ int acc[BK * 3];                   // 12 KB
    const int b = blockIdx.x >> 4;                // / S2
    const int q = blockIdx.x & (S2 - 1);          // % S2
    for (int t = threadIdx.x; t < BK * 3; t += T) acc[t] = 0;
    __syncthreads();
    const unsigned len = gcur[b];
    const unsigned s0  = (unsigned)b * (unsigned)cap;   // cap even -> 16B align
    unsigned chunk = (((len + S2 - 1) / S2) + 1) & ~1u; // even chunks
    const unsigned c0 = min(len, q * chunk);
    const unsigned c1 = min(len, c0 + chunk);
    for (unsigned i = c0 + 2 * threadIdx.x; i < c1; i += 2 * T) {
        if (i + 1 < c1) {
            int4 v = *(const int4*)(sorted + s0 + i);   // two entries
            int lid0 = ((unsigned)v.y) >> 16;
            atomicAdd(&acc[lid0 * 3 + 0], (int)(short)(v.x & 0xffff));
            atomicAdd(&acc[lid0 * 3 + 1], v.x >> 16);
            atomicAdd(&acc[lid0 * 3 + 2], (int)(short)(v.y & 0xffff));
            int lid1 = ((unsigned)v.w) >> 16;
            atomicAdd(&acc[lid1 * 3 + 0], (int)(short)(v.z & 0xffff));
            atomicAdd(&acc[lid1 * 3 + 1], v.z >> 16);
            atomicAdd(&acc[lid1 * 3 + 2], (int)(short)(v.w & 0xffff));
        } else {
            int2 v = sorted[s0 + i];
            int lid0 = ((unsigned)v.y) >> 16;
            atomicAdd(&acc[lid0 * 3 + 0], (int)(short)(v.x & 0xffff));
            atomicAdd(&acc[lid0 * 3 + 1], v.x >> 16);
            atomicAdd(&acc[lid0 * 3 + 2], (int)(short)(v.y & 0xffff));
        }
    }
    __syncthreads();
    int* A = accum + (size_t)b * (BK * 3);        // == &accum[node0*3]
    for (int t = threadIdx.x; t < BK * 3; t += T) {
        int v = acc[t];
        if (v) atomicAdd(&A[t], v);               // coalesced global int atomics
    }
}

// ------- Phase 4b: convert int accumulator, write both outputs --------------
__global__ __launch_bounds__(T)
void p4b_convert(const int* __restrict__ accum, float* __restrict__ forces,
                 float* __restrict__ analytic, int N)
{
    const int i = blockIdx.x * T + threadIdx.x;   // output component idx in [0, 3N)
    if (i >= 3 * N) return;
    float v = (float)accum[i] * INV_FPSCALE;
    analytic[i] = v;
    forces[i] = -0.5f * v;
}

// ---------------- Fallback (R1 kernel) if workspace too small ---------------
__global__ __launch_bounds__(T)
void lj_fallback(const float* __restrict__ bv, const int* __restrict__ dst,
                 float* __restrict__ out_energy, float* __restrict__ analytic, int E)
{
    const int e = blockIdx.x * blockDim.x + threadIdx.x;
    float esum = 0.0f;
    if (e < E) {
        float x = bv[3 * e], y = bv[3 * e + 1], z = bv[3 * e + 2];
        float r2 = x * x + y * y + z * z;
        float inv = 1.0f / r2;
        float c6 = inv * inv * inv, c12 = c6 * c6;
        esum = 2.0f * (c12 - c6) + HALF_NEG_E0;
        float fs = -24.0f * (2.0f * c12 - c6) * inv;
        float* p = analytic + 3 * (size_t)dst[e];
        unsafeAtomicAdd(p + 0, fs * x);
        unsafeAtomicAdd(p + 1, fs * y);
        unsafeAtomicAdd(p + 2, fs * z);
    }
#pragma unroll
    for (int off = 32; off > 0; off >>= 1) esum += __shfl_down(esum, off, 64);
    __shared__ float wsum[T / 64];
    if ((threadIdx.x & 63) == 0) wsum[threadIdx.x >> 6] = esum;
    __syncthreads();
    if (threadIdx.x == 0) {
        float s = 0.0f;
        for (int w = 0; w < T / 64; ++w) s += wsum[w];
        unsafeAtomicAdd(out_energy, s);
    }
}

__global__ __launch_bounds__(T)
void lj_scale(const float* __restrict__ analytic, float* __restrict__ forces, int n)
{
    int i = blockIdx.x * blockDim.x + threadIdx.x;
    if (i < n) forces[i] = -0.5f * analytic[i];
}

extern "C" void kernel_launch(void* const* d_in, const int* in_sizes, int n_in,
                              void* d_out, int out_size, void* d_ws, size_t ws_size,
                              hipStream_t stream)
{
    const float* bv  = (const float*)d_in[0];
    const int*   dst = (const int*)d_in[1];
    const int E = in_sizes[0] / 3;
    const int N = (out_size - 1) / 6;   // out = [energy | forces(3N) | analytic(3N)]

    float* out      = (float*)d_out;
    float* energy   = out;
    float* forces   = out + 1;
    float* analytic = out + 1 + (size_t)3 * N;

    const int NB = (N + BK - 1) / BK;
    const int G  = (E + 3) / 4;
    // exactly <=2 int4-groups per thread in p3
    int B1 = (G + 2 * T - 1) / (2 * T);
    if (B1 < 1) B1 = 1;
    const int GPB = (G + B1 - 1) / B1;

    // per-bucket region capacity: mean + 10 sigma + 64, rounded even
    const int avg = E / NB;
    int cap = avg + 10 * (int)ceil(sqrt((double)avg)) + 64;
    cap = (cap + 1) & ~1;

    auto al = [](size_t x) { return (x + 255) & ~(size_t)255; };
    const size_t sorted_bytes = al((size_t)NB * cap * 8);
    const size_t gcur_bytes   = al((size_t)NB * 4);
    const size_t accum_bytes  = al((size_t)NB * (BK * 3) * 4);
    const size_t need = sorted_bytes + gcur_bytes + accum_bytes;

    const int capb = GPB * 4;
    // staging int2[capb] + uchar[capb] (rounded to ints) + 2*NB ints
    const size_t smem_bytes = (size_t)capb * 8 + ((size_t)(capb + 3) / 4) * 4
                            + (size_t)2 * NB * 4;

    if (NB <= 128 && capb >= 128 && GPB <= 2 * T && smem_bytes <= 64000
        && ws_size >= need) {
        char* w = (char*)d_ws;
        int2*     sorted = (int2*)w;     w += sorted_bytes;
        unsigned* gcur   = (unsigned*)w; w += gcur_bytes;
        int*      accum  = (int*)w;

        hipMemsetAsync(gcur, 0, (size_t)NB * 4, stream);
        hipMemsetAsync(accum, 0, (size_t)NB * (BK * 3) * 4, stream);
        hipMemsetAsync(energy, 0, sizeof(float), stream);
        p3_fused   <<<B1, T, smem_bytes, stream>>>(bv, dst, gcur, sorted, energy,
                                                   E, NB, GPB, cap);
        p4a_reduce <<<NB * S2, T, 0, stream>>>(sorted, gcur, accum, cap);
        p4b_convert<<<(3 * N + T - 1) / T, T, 0, stream>>>(accum, forces, analytic, N);
    } else {
        hipMemsetAsync(d_out, 0, (size_t)out_size * sizeof(float), stream);
        lj_fallback<<<(E + T - 1) / T, T, 0, stream>>>(bv, dst, energy, analytic, E);
        const int n3 = 3 * N;
        lj_scale<<<(n3 + T - 1) / T, T, 0, stream>>>(analytic, forces, n3);
    }
}